// Round 11
// baseline (171.977 us; speedup 1.0000x reference)
//
#include <hip/hip_runtime.h>
#include <stdint.h>

typedef unsigned long long u64;
typedef unsigned int u32;

#define WORDS_PER_IMG 16384
#define PIXELS_PER_IMG (1024*1024)

// skeletonize strip geometry: 10 strips x 112 owned rows, 8-row halo
#define SOWN 112
#define SHALO 8
#define SROWS 128
#define SPAD 17
#define NSTRIP 10

// ---------------- K1: bitpack target (32 px/thread, 8x int4 loads) ----------------
__global__ __launch_bounds__(256) void k_pack(const int* __restrict__ tgt,
                                              u64* __restrict__ bits,
                                              u32* __restrict__ cpart) {
    __shared__ u32 marr[256];
    __shared__ u32 ws_[4];
    int t = threadIdx.x;
    const int4* p4 = (const int4*)(tgt + ((size_t)blockIdx.x * 256 + t) * 32);
    int4 v[8];
    #pragma unroll
    for (int k = 0; k < 8; ++k) v[k] = p4[k];       // 8 loads in flight
    u32 m32 = 0;
    #pragma unroll
    for (int k = 0; k < 8; ++k) {
        m32 |= (u32)(v[k].x & 1) << (4 * k + 0);
        m32 |= (u32)(v[k].y & 1) << (4 * k + 1);
        m32 |= (u32)(v[k].z & 1) << (4 * k + 2);
        m32 |= (u32)(v[k].w & 1) << (4 * k + 3);
    }
    marr[t] = m32;
    u32 cnt = __popc(m32);
    for (int off = 32; off; off >>= 1) cnt += __shfl_down(cnt, off, 64);
    if ((t & 63) == 0) ws_[t >> 6] = cnt;
    __syncthreads();
    if (t < 128)
        bits[(size_t)blockIdx.x * 128 + t] = ((const u64*)marr)[t];
    if (t == 0) cpart[blockIdx.x] = ws_[0] + ws_[1] + ws_[2] + ws_[3];
}

// ---------------- K2: skeletonize (320 blocks) + block-0 weight table ----------------
__global__ __launch_bounds__(256) void k_skel(const u64* __restrict__ bits,
                                              u64* __restrict__ fore,
                                              u64* __restrict__ back,
                                              const u32* __restrict__ cpart,
                                              const int* __restrict__ epochp,
                                              float4* __restrict__ wtab,
                                              u64* __restrict__ acc64,
                                              u32* __restrict__ ctr) {
    __shared__ u64 bufA[SROWS][SPAD];
    __shared__ u64 bufB[SROWS][SPAD];
    __shared__ int nzbuf[2];

    int t   = threadIdx.x;
    int bid = blockIdx.x;

    if (bid == 0) {
        if (t == 0) { *acc64 = 0ull; *ctr = 0u; }   // reset for k_loss (every launch)
        int bb = t >> 4, sl = t & 15;        // 16 batches x 16 lanes
        u32 c = 0;
        #pragma unroll
        for (int k = 0; k < 8; ++k) c += cpart[(bb << 7) + (sl << 3) + k];
        #pragma unroll
        for (int off = 8; off; off >>= 1) c += __shfl_down(c, off, 16);
        if (sl == 0) {
            float c1 = (float)c;
            float c0 = (float)PIXELS_PER_IMG - c1;
            float mn = fminf(c0, c1);
            float w0 = c1 / mn;
            float w1 = c0 / mn;
            float factor = fminf((float)epochp[0] / 50.0f, 1.0f);
            wtab[bb] = make_float4(w0, w1, factor, 0.0f);
        }
    }

    int task  = bid / NSTRIP;
    int strip = bid - task * NSTRIP;
    int batch = task >> 1;
    int pol   = task & 1;
    int r0    = strip * SOWN - SHALO;
    const u64* img = bits + batch * WORDS_PER_IMG;

    int r  = t >> 1;
    int h  = t & 1;
    int w0 = h << 3;
    int y  = r0 + r;
    bool yok   = ((unsigned)y < 1024u);
    bool owned = yok && (r >= SHALO) && (r < SHALO + SOWN);

    u64 (*E)[SPAD]  = bufA;
    u64 (*Er)[SPAD] = bufB;

    if (yok) {
        const u64* src = img + (y << 4) + w0;
        #pragma unroll
        for (int k = 0; k < 8; ++k) {
            u64 v = src[k];
            E[r][w0 + k] = pol ? ~v : v;
        }
    } else {
        #pragma unroll
        for (int k = 0; k < 8; ++k) E[r][w0 + k] = 0;
    }
    if (t < 2) nzbuf[t] = 0;

    u64 s[8] = {0,0,0,0,0,0,0,0};
    u64 corig[8];

    auto ldwin = [&](u64 (*B)[SPAD], int rr, u64 oob, u64* d) {
        int yy = r0 + rr;
        if (rr >= 0 && rr < SROWS && (unsigned)yy < 1024u) {
            d[0] = (w0 > 0) ? B[rr][w0 - 1] : oob;
            #pragma unroll
            for (int k = 0; k < 8; ++k) d[k + 1] = B[rr][w0 + k];
            d[9] = (w0 + 8 < 16) ? B[rr][w0 + 8] : oob;
        } else {
            #pragma unroll
            for (int k = 0; k < 10; ++k) d[k] = oob;
        }
    };
    #define HOR_E(d, k) (d[k] & ((d[k] << 1) | (d[k-1] >> 63)) & ((d[k] >> 1) | (d[k+1] << 63)))
    #define HOR_D(d, k) (d[k] | (d[k] << 1) | (d[k-1] >> 63) | (d[k] >> 1) | (d[k+1] << 63))

    __syncthreads();
    for (int it = 0; it < 32; ++it) {
        u64 rm[10], rc[10], rp[10];
        ldwin(E, r - 1, ~0ull, rm);
        ldwin(E, r,     ~0ull, rc);
        ldwin(E, r + 1, ~0ull, rp);
        u64 any = 0;
        #pragma unroll
        for (int k = 0; k < 8; ++k) {
            u64 v = HOR_E(rm, k + 1) & HOR_E(rc, k + 1) & HOR_E(rp, k + 1);
            if (!yok) v = 0;
            any |= v;
            corig[k] = rc[k + 1];
            Er[r][w0 + k] = v;
        }
        u64 bal = __ballot(any != 0);
        if (bal && (t & 63) == 0) atomicOr(&nzbuf[it & 1], 1);
        if (t == 0) nzbuf[(it + 1) & 1] = 0;
        __syncthreads();
        if (nzbuf[it & 1] == 0) {
            if (owned) {
                #pragma unroll
                for (int k = 0; k < 8; ++k) s[k] |= corig[k];
            }
            break;
        }
        if (owned) {
            u64 dm[10], dc[10], dp[10];
            ldwin(Er, r - 1, 0ull, dm);
            ldwin(Er, r,     0ull, dc);
            ldwin(Er, r + 1, 0ull, dp);
            #pragma unroll
            for (int k = 0; k < 8; ++k) {
                u64 op = HOR_D(dm, k + 1) | HOR_D(dc, k + 1) | HOR_D(dp, k + 1);
                s[k] |= corig[k] & ~op;
            }
        }
        { u64 (*tmp)[SPAD] = E; E = Er; Er = tmp; }
        __syncthreads();
    }

    if (owned) {
        u64* plane = (pol ? back : fore) + batch * WORDS_PER_IMG + (y << 4) + w0;
        #pragma unroll
        for (int k = 0; k < 8; ++k) plane[k] = s[k];
    }
    #undef HOR_E
    #undef HOR_D
}

// ---------------- K3: fused loss, 16 px/thread + fixed-point atomic reduce ----------------
__global__ __launch_bounds__(256) void k_loss(
    const float* __restrict__ pred,
    const u64* __restrict__ bits,
    const u64* __restrict__ fore,
    const u64* __restrict__ back,
    const float4* __restrict__ wtab,
    u64* __restrict__ acc64,
    u32* __restrict__ ctr,
    float* __restrict__ out)
{
    const float LOG2E = 1.4426950408889634f;
    const float LN2   = 0.6931471805599453f;

    __shared__ u64 tb[4][16], tf[4][16], tbk[6][16], dil[4][16];
    __shared__ float wsum[4];

    int bid = blockIdx.x;           // 4096 blocks; 256 per batch
    int b   = bid >> 8;
    int rp  = bid & 255;
    int y0  = rp << 2;              // 4 rows per block
    int t   = threadIdx.x;
    int base = b << 14;

    int ry = t >> 6;                // 0..3
    int xq = t & 63;
    int y  = y0 + ry;

    const float*  pb  = pred + (size_t)b * (2 * PIXELS_PER_IMG);
    const float4* r0p = (const float4*)(pb + (y << 10));
    const float4* r1p = (const float4*)(pb + PIXELS_PER_IMG + (y << 10));

    // 8 loads issued up-front (named, never arrays)
    float4 a0 = r0p[xq];
    float4 a1 = r0p[xq + 64];
    float4 a2 = r0p[xq + 128];
    float4 a3 = r0p[xq + 192];
    float4 c0 = r1p[xq];
    float4 c1 = r1p[xq + 64];
    float4 c2 = r1p[xq + 128];
    float4 c3 = r1p[xq + 192];
    float4 wt = wtab[b];

    // stage bit-planes
    if (t < 64) {
        int i = t >> 4, w = t & 15;
        tb[i][w] = bits[base + ((y0 + i) << 4) + w];
    } else if (t < 128) {
        int tt2 = t - 64; int i = tt2 >> 4, w = tt2 & 15;
        tf[i][w] = fore[base + ((y0 + i) << 4) + w];
    } else if (t < 224) {
        int tt2 = t - 128; int i = tt2 >> 4, w = tt2 & 15;   // i in 0..5
        int yy = y0 - 1 + i;
        tbk[i][w] = ((unsigned)yy < 1024u) ? back[base + (yy << 4) + w] : 0ull;
    }
    __syncthreads();
    if (t < 64) {
        int i = t >> 4, w = t & 15;
        u64 m0 = tbk[i][w] | tbk[i + 1][w] | tbk[i + 2][w];
        u64 mL = (w > 0)  ? (tbk[i][w - 1] | tbk[i + 1][w - 1] | tbk[i + 2][w - 1]) : 0ull;
        u64 mR = (w < 15) ? (tbk[i][w + 1] | tbk[i + 1][w + 1] | tbk[i + 2][w + 1]) : 0ull;
        dil[i][w] = m0 | (m0 << 1) | (mL >> 63) | (m0 >> 1) | (mR << 63);
    }
    __syncthreads();

    float w0 = wt.x, w1 = wt.y, factor = wt.z;
    int wbase = xq >> 4;            // word 0..3 (+4 per chunk k)
    int j     = (xq & 15) << 2;     // nibble shift within word
    float acc = 0.f;

    auto do1 = [&](float av, float cv, u32 tn, u32 fn, u32 bn, int i) {
        u32 tt  = (tn >> i) & 1u;
        float fb = (float)((fn >> i) & 1u) + (float)((bn >> i) & 1u);
        float wmap = fmaf(factor, fb, 1.0f);
        float cw = tt ? w1 : w0;
        float diff = cv - av;                       // p1 - p0
        float sd = __uint_as_float(__float_as_uint(diff) ^ (tt << 31));  // p_other - p_t
        float e  = __builtin_amdgcn_exp2f(sd * LOG2E);
        float ce = LN2 * __builtin_amdgcn_logf(1.0f + e);
        acc = fmaf(wmap * cw, ce, acc);
    };
    auto do4 = [&](float4 a, float4 c, int k) {
        int wk = wbase + (k << 2);
        u32 tn = (u32)(tb[ry][wk]  >> j) & 15u;
        u32 fn = (u32)(tf[ry][wk]  >> j) & 15u;
        u32 bn = (u32)(dil[ry][wk] >> j) & 15u;
        do1(a.x, c.x, tn, fn, bn, 0);
        do1(a.y, c.y, tn, fn, bn, 1);
        do1(a.z, c.z, tn, fn, bn, 2);
        do1(a.w, c.w, tn, fn, bn, 3);
    };
    do4(a0, c0, 0);
    do4(a1, c1, 1);
    do4(a2, c2, 2);
    do4(a3, c3, 3);

    for (int off = 32; off; off >>= 1) acc += __shfl_down(acc, off, 64);
    if ((t & 63) == 0) wsum[t >> 6] = acc;
    __syncthreads();

    if (t == 0) {
        float p = wsum[0] + wsum[1] + wsum[2] + wsum[3];
        // fixed-point 2^24: integer adds commute -> deterministic across replays
        long long q = (long long)llrint((double)p * 16777216.0);
        atomicAdd(acc64, (u64)q);
        __threadfence();
        u32 old = atomicAdd(ctr, 1u);
        if (old == 4095u) {            // last block: finalize
            __threadfence();
            u64 total = atomicAdd(acc64, 0ull);   // coherent read at L2 point
            out[0] = (float)((double)(long long)total / 16777216.0 / 16777216.0);
        }
    }
}

extern "C" void kernel_launch(void* const* d_in, const int* in_sizes, int n_in,
                              void* d_out, int out_size, void* d_ws, size_t ws_size,
                              hipStream_t stream) {
    const float* pred   = (const float*)d_in[0];
    const int*   target = (const int*)d_in[1];
    const int*   epoch  = (const int*)d_in[2];

    char* ws = (char*)d_ws;
    u64*    acc64    = (u64*)ws;                   // 8 B
    u32*    ctr      = (u32*)(ws + 64);            // 4 B
    float4* wtab     = (float4*)(ws + 256);        // 256 B
    u32*    cpart    = (u32*)(ws + 4096);          // 8 KB (2048 u32)
    u64*    bits     = (u64*)(ws + (1u << 20));    // 2 MB
    u64*    fore     = (u64*)(ws + (3u << 20));    // 2 MB
    u64*    back     = (u64*)(ws + (5u << 20));    // 2 MB

    hipLaunchKernelGGL(k_pack, dim3(2048), dim3(256), 0, stream, target, bits, cpart);
    hipLaunchKernelGGL(k_skel, dim3(320),  dim3(256), 0, stream, bits, fore, back,
                       cpart, epoch, wtab, acc64, ctr);
    hipLaunchKernelGGL(k_loss, dim3(4096), dim3(256), 0, stream, pred, bits, fore, back,
                       wtab, acc64, ctr, (float*)d_out);
}

// Round 12
// 53.625 us; speedup vs baseline: 3.2070x; 3.2070x over previous
//
#include <hip/hip_runtime.h>
#include <stdint.h>

typedef unsigned long long u64;
typedef unsigned int u32;

#define WORDS_PER_IMG 16384
#define PIXELS_PER_IMG (1024*1024)

// skeletonize strip geometry: 10 strips x 112 owned rows, 8-row halo
#define SOWN 112
#define SHALO 8
#define SROWS 128
#define SPAD 17
#define NSTRIP 10

// ---------------- K1: bitpack target (32 px/thread, 8x int4 loads) ----------------
__global__ __launch_bounds__(256) void k_pack(const int* __restrict__ tgt,
                                              u64* __restrict__ bits,
                                              u32* __restrict__ cpart) {
    __shared__ u32 marr[256];
    __shared__ u32 ws_[4];
    int t = threadIdx.x;
    const int4* p4 = (const int4*)(tgt + ((size_t)blockIdx.x * 256 + t) * 32);
    int4 v[8];
    #pragma unroll
    for (int k = 0; k < 8; ++k) v[k] = p4[k];       // 8 loads in flight
    u32 m32 = 0;
    #pragma unroll
    for (int k = 0; k < 8; ++k) {
        m32 |= (u32)(v[k].x & 1) << (4 * k + 0);
        m32 |= (u32)(v[k].y & 1) << (4 * k + 1);
        m32 |= (u32)(v[k].z & 1) << (4 * k + 2);
        m32 |= (u32)(v[k].w & 1) << (4 * k + 3);
    }
    marr[t] = m32;
    u32 cnt = __popc(m32);
    for (int off = 32; off; off >>= 1) cnt += __shfl_down(cnt, off, 64);
    if ((t & 63) == 0) ws_[t >> 6] = cnt;
    __syncthreads();
    if (t < 128)
        bits[(size_t)blockIdx.x * 128 + t] = ((const u64*)marr)[t];
    if (t == 0) cpart[blockIdx.x] = ws_[0] + ws_[1] + ws_[2] + ws_[3];
}

// ---------------- K2: skeletonize (320 blocks) + block-0 weight table ----------------
__global__ __launch_bounds__(256) void k_skel(const u64* __restrict__ bits,
                                              u64* __restrict__ fore,
                                              u64* __restrict__ back,
                                              const u32* __restrict__ cpart,
                                              const int* __restrict__ epochp,
                                              float4* __restrict__ wtab) {
    __shared__ u64 bufA[SROWS][SPAD];
    __shared__ u64 bufB[SROWS][SPAD];
    __shared__ int nzbuf[2];

    int t   = threadIdx.x;
    int bid = blockIdx.x;

    if (bid == 0) {
        int bb = t >> 4, sl = t & 15;        // 16 batches x 16 lanes
        u32 c = 0;
        #pragma unroll
        for (int k = 0; k < 8; ++k) c += cpart[(bb << 7) + (sl << 3) + k];
        #pragma unroll
        for (int off = 8; off; off >>= 1) c += __shfl_down(c, off, 16);
        if (sl == 0) {
            float c1 = (float)c;
            float c0 = (float)PIXELS_PER_IMG - c1;
            float mn = fminf(c0, c1);
            float w0 = c1 / mn;
            float w1 = c0 / mn;
            float factor = fminf((float)epochp[0] / 50.0f, 1.0f);
            wtab[bb] = make_float4(w0, w1, factor, 0.0f);
        }
    }

    int task  = bid / NSTRIP;
    int strip = bid - task * NSTRIP;
    int batch = task >> 1;
    int pol   = task & 1;
    int r0    = strip * SOWN - SHALO;
    const u64* img = bits + batch * WORDS_PER_IMG;

    int r  = t >> 1;
    int h  = t & 1;
    int w0 = h << 3;
    int y  = r0 + r;
    bool yok   = ((unsigned)y < 1024u);
    bool owned = yok && (r >= SHALO) && (r < SHALO + SOWN);

    u64 (*E)[SPAD]  = bufA;
    u64 (*Er)[SPAD] = bufB;

    if (yok) {
        const u64* src = img + (y << 4) + w0;
        #pragma unroll
        for (int k = 0; k < 8; ++k) {
            u64 v = src[k];
            E[r][w0 + k] = pol ? ~v : v;
        }
    } else {
        #pragma unroll
        for (int k = 0; k < 8; ++k) E[r][w0 + k] = 0;
    }
    if (t < 2) nzbuf[t] = 0;

    u64 s[8] = {0,0,0,0,0,0,0,0};
    u64 corig[8];

    auto ldwin = [&](u64 (*B)[SPAD], int rr, u64 oob, u64* d) {
        int yy = r0 + rr;
        if (rr >= 0 && rr < SROWS && (unsigned)yy < 1024u) {
            d[0] = (w0 > 0) ? B[rr][w0 - 1] : oob;
            #pragma unroll
            for (int k = 0; k < 8; ++k) d[k + 1] = B[rr][w0 + k];
            d[9] = (w0 + 8 < 16) ? B[rr][w0 + 8] : oob;
        } else {
            #pragma unroll
            for (int k = 0; k < 10; ++k) d[k] = oob;
        }
    };
    #define HOR_E(d, k) (d[k] & ((d[k] << 1) | (d[k-1] >> 63)) & ((d[k] >> 1) | (d[k+1] << 63)))
    #define HOR_D(d, k) (d[k] | (d[k] << 1) | (d[k-1] >> 63) | (d[k] >> 1) | (d[k+1] << 63))

    __syncthreads();
    for (int it = 0; it < 32; ++it) {
        u64 rm[10], rc[10], rp[10];
        ldwin(E, r - 1, ~0ull, rm);
        ldwin(E, r,     ~0ull, rc);
        ldwin(E, r + 1, ~0ull, rp);
        u64 any = 0;
        #pragma unroll
        for (int k = 0; k < 8; ++k) {
            u64 v = HOR_E(rm, k + 1) & HOR_E(rc, k + 1) & HOR_E(rp, k + 1);
            if (!yok) v = 0;
            any |= v;
            corig[k] = rc[k + 1];
            Er[r][w0 + k] = v;
        }
        u64 bal = __ballot(any != 0);
        if (bal && (t & 63) == 0) atomicOr(&nzbuf[it & 1], 1);
        if (t == 0) nzbuf[(it + 1) & 1] = 0;
        __syncthreads();
        if (nzbuf[it & 1] == 0) {
            if (owned) {
                #pragma unroll
                for (int k = 0; k < 8; ++k) s[k] |= corig[k];
            }
            break;
        }
        if (owned) {
            u64 dm[10], dc[10], dp[10];
            ldwin(Er, r - 1, 0ull, dm);
            ldwin(Er, r,     0ull, dc);
            ldwin(Er, r + 1, 0ull, dp);
            #pragma unroll
            for (int k = 0; k < 8; ++k) {
                u64 op = HOR_D(dm, k + 1) | HOR_D(dc, k + 1) | HOR_D(dp, k + 1);
                s[k] |= corig[k] & ~op;
            }
        }
        { u64 (*tmp)[SPAD] = E; E = Er; Er = tmp; }
        __syncthreads();
    }

    if (owned) {
        u64* plane = (pol ? back : fore) + batch * WORDS_PER_IMG + (y << 4) + w0;
        #pragma unroll
        for (int k = 0; k < 8; ++k) plane[k] = s[k];
    }
    #undef HOR_E
    #undef HOR_D
}

// ---------------- K3: fused loss, 16 px/thread, named float4s, direct softplus ----------------
__global__ __launch_bounds__(256) void k_loss(
    const float* __restrict__ pred,
    const u64* __restrict__ bits,
    const u64* __restrict__ fore,
    const u64* __restrict__ back,
    const float4* __restrict__ wtab,
    float* __restrict__ partials)
{
    const float LOG2E = 1.4426950408889634f;
    const float LN2   = 0.6931471805599453f;

    __shared__ u64 tb[4][16], tf[4][16], tbk[6][16], dil[4][16];
    __shared__ float wsum[4];

    int bid = blockIdx.x;           // 4096 blocks; 256 per batch
    int b   = bid >> 8;
    int rp  = bid & 255;
    int y0  = rp << 2;              // 4 rows per block
    int t   = threadIdx.x;
    int base = b << 14;

    int ry = t >> 6;                // 0..3
    int xq = t & 63;
    int y  = y0 + ry;

    const float*  pb  = pred + (size_t)b * (2 * PIXELS_PER_IMG);
    const float4* r0p = (const float4*)(pb + (y << 10));
    const float4* r1p = (const float4*)(pb + PIXELS_PER_IMG + (y << 10));

    // 8 loads issued up-front (named, never arrays)
    float4 a0 = r0p[xq];
    float4 a1 = r0p[xq + 64];
    float4 a2 = r0p[xq + 128];
    float4 a3 = r0p[xq + 192];
    float4 c0 = r1p[xq];
    float4 c1 = r1p[xq + 64];
    float4 c2 = r1p[xq + 128];
    float4 c3 = r1p[xq + 192];
    float4 wt = wtab[b];

    // stage bit-planes
    if (t < 64) {
        int i = t >> 4, w = t & 15;
        tb[i][w] = bits[base + ((y0 + i) << 4) + w];
    } else if (t < 128) {
        int tt2 = t - 64; int i = tt2 >> 4, w = tt2 & 15;
        tf[i][w] = fore[base + ((y0 + i) << 4) + w];
    } else if (t < 224) {
        int tt2 = t - 128; int i = tt2 >> 4, w = tt2 & 15;   // i in 0..5
        int yy = y0 - 1 + i;
        tbk[i][w] = ((unsigned)yy < 1024u) ? back[base + (yy << 4) + w] : 0ull;
    }
    __syncthreads();
    if (t < 64) {
        int i = t >> 4, w = t & 15;
        u64 m0 = tbk[i][w] | tbk[i + 1][w] | tbk[i + 2][w];
        u64 mL = (w > 0)  ? (tbk[i][w - 1] | tbk[i + 1][w - 1] | tbk[i + 2][w - 1]) : 0ull;
        u64 mR = (w < 15) ? (tbk[i][w + 1] | tbk[i + 1][w + 1] | tbk[i + 2][w + 1]) : 0ull;
        dil[i][w] = m0 | (m0 << 1) | (mL >> 63) | (m0 >> 1) | (mR << 63);
    }
    __syncthreads();

    float w0 = wt.x, w1 = wt.y, factor = wt.z;
    int wbase = xq >> 4;            // word 0..3 (+4 per chunk k)
    int j     = (xq & 15) << 2;     // nibble shift within word
    float acc = 0.f;

    auto do1 = [&](float av, float cv, u32 tn, u32 fn, u32 bn, int i) {
        u32 tt  = (tn >> i) & 1u;
        float fb = (float)((fn >> i) & 1u) + (float)((bn >> i) & 1u);
        float wmap = fmaf(factor, fb, 1.0f);
        float cw = tt ? w1 : w0;
        float diff = cv - av;                       // p1 - p0
        float sd = __uint_as_float(__float_as_uint(diff) ^ (tt << 31));  // p_other - p_t
        float e  = __builtin_amdgcn_exp2f(sd * LOG2E);
        float ce = LN2 * __builtin_amdgcn_logf(1.0f + e);
        acc = fmaf(wmap * cw, ce, acc);
    };
    auto do4 = [&](float4 a, float4 c, int k) {
        int wk = wbase + (k << 2);
        u32 tn = (u32)(tb[ry][wk]  >> j) & 15u;
        u32 fn = (u32)(tf[ry][wk]  >> j) & 15u;
        u32 bn = (u32)(dil[ry][wk] >> j) & 15u;
        do1(a.x, c.x, tn, fn, bn, 0);
        do1(a.y, c.y, tn, fn, bn, 1);
        do1(a.z, c.z, tn, fn, bn, 2);
        do1(a.w, c.w, tn, fn, bn, 3);
    };
    do4(a0, c0, 0);
    do4(a1, c1, 1);
    do4(a2, c2, 2);
    do4(a3, c3, 3);

    for (int off = 32; off; off >>= 1) acc += __shfl_down(acc, off, 64);
    if ((t & 63) == 0) wsum[t >> 6] = acc;
    __syncthreads();
    if (t == 0)
        partials[bid] = wsum[0] + wsum[1] + wsum[2] + wsum[3];
}

// ---------------- K4: final reduce (4096 partials) ----------------
__global__ __launch_bounds__(256) void k_reduce(const float* __restrict__ partials,
                                                float* __restrict__ out) {
    double acc = 0.0;
    for (int i = threadIdx.x; i < 4096; i += 256) acc += (double)partials[i];
    for (int off = 32; off; off >>= 1) acc += __shfl_down(acc, off, 64);
    __shared__ double sd[4];
    if ((threadIdx.x & 63) == 0) sd[threadIdx.x >> 6] = acc;
    __syncthreads();
    if (threadIdx.x == 0)
        out[0] = (float)((sd[0] + sd[1] + sd[2] + sd[3]) / 16777216.0);
}

extern "C" void kernel_launch(void* const* d_in, const int* in_sizes, int n_in,
                              void* d_out, int out_size, void* d_ws, size_t ws_size,
                              hipStream_t stream) {
    const float* pred   = (const float*)d_in[0];
    const int*   target = (const int*)d_in[1];
    const int*   epoch  = (const int*)d_in[2];

    char* ws = (char*)d_ws;
    float4* wtab     = (float4*)(ws + 256);        // 256 B
    u32*    cpart    = (u32*)(ws + 4096);          // 8 KB (2048 u32)
    float*  partials = (float*)(ws + (1u << 17));  // 16 KB @ 128K
    u64*    bits     = (u64*)(ws + (1u << 20));    // 2 MB
    u64*    fore     = (u64*)(ws + (3u << 20));    // 2 MB
    u64*    back     = (u64*)(ws + (5u << 20));    // 2 MB

    hipLaunchKernelGGL(k_pack,   dim3(2048), dim3(256), 0, stream, target, bits, cpart);
    hipLaunchKernelGGL(k_skel,   dim3(320),  dim3(256), 0, stream, bits, fore, back,
                       cpart, epoch, wtab);
    hipLaunchKernelGGL(k_loss,   dim3(4096), dim3(256), 0, stream, pred, bits, fore, back,
                       wtab, partials);
    hipLaunchKernelGGL(k_reduce, dim3(1),    dim3(256), 0, stream, partials, (float*)d_out);
}